// Round 7
// baseline (976.238 us; speedup 1.0000x reference)
//
#include <hip/hip_runtime.h>

#define Hh 64
#define INPUT 3
#define OUTD 2
#define BATCH 1024
#define TENC 512
#define PLEN 300

#define LOG2E 1.44269504088896340736f

typedef float v2f __attribute__((ext_vector_type(2)));

__device__ __forceinline__ float exp2_(float x) { return __builtin_amdgcn_exp2f(x); }
__device__ __forceinline__ float rcp_(float x)  { return __builtin_amdgcn_rcpf(x); }
__device__ __forceinline__ float tanh_(float x) {
    float t = exp2_(x * (2.0f * LOG2E));
    return fmaf(-2.0f, rcp_(1.0f + t), 1.0f);
}

// quad broadcast via DPP: all 4 lanes of a quad get quad-lane Q's value
#define QUADB(dst, src, pat)                                                   \
    dst = __int_as_float(__builtin_amdgcn_update_dpp(                          \
        0, __float_as_int(src), (pat), 0xF, 0xF, true))

// xor-4 within 32-lane groups (BitMode: and=0x1F, or=0, xor=4)
#define SWZ_XOR4(x) __int_as_float(__builtin_amdgcn_ds_swizzle(__float_as_int(x), 0x101F))

#define PKFMA(acc, w, hv) (acc) = __builtin_elementwise_fma((w), (hv), (acc))

// one chunk: 2 ds_read_b128 of h + 4 pk_fma, then a scheduling fence so the
// compiler cannot hoist every h-load to the top (the register-pressure spike
// that has been pushing the weights into AGPRs on every previous round)
#define CHUNK(MA, MB, MC, MD, J)                                               \
    {                                                                          \
        const float4 A = hq[2 * (J)];                                          \
        const float4 B = hq[2 * (J) + 1];                                      \
        PKFMA(a0, MA, ((v2f){A.x, A.y}));                                      \
        PKFMA(a1, MB, ((v2f){A.z, A.w}));                                      \
        PKFMA(a0, MC, ((v2f){B.x, B.y}));                                      \
        PKFMA(a1, MD, ((v2f){B.z, B.w}));                                      \
        __builtin_amdgcn_sched_barrier(0);                                     \
    }

__global__ __launch_bounds__(512, 4)
void lstm_forecast_kernel(const float* __restrict__ x,
                          const float* __restrict__ force,
                          const float* __restrict__ W_ih,
                          const float* __restrict__ W_hh,
                          const float* __restrict__ b_ih,
                          const float* __restrict__ b_hh,
                          const float* __restrict__ W_out,
                          const float* __restrict__ b_out,
                          float* __restrict__ out)
{
    const int tid  = threadIdx.x;
    const int lane = tid & 63;
    const int wv   = tid >> 6;            // wave 0..7
    const int g    = lane & 3;            // gate 0=i 1=f 2=g 3=o
    const int half = (lane >> 2) & 1;     // which 32-col half of the row
    const int ulo  = lane >> 3;           // unit-local 0..7
    const int u    = wv * 8 + ulo;        // hidden unit 0..63
    const int row  = (g << 6) + u;        // weight row
    const int b    = blockIdx.x;

    __shared__ __align__(16) float x_s[TENC * 4];   // 8 KB, [t*4+c] padded
    __shared__ __align__(16) float f_s[PLEN - 1];   // ~1.2 KB
    __shared__ __align__(16) float h_s[2][Hh];      // 512 B double-buffered
    __shared__ __align__(16) float y_s[2][2][8];    // 128 B [ph][out][wv]

    // ---- stage x / force (coalesced reads, stride-4 padded x writes) ----
    const float* xb = x + (size_t)b * (TENC * INPUT);
    for (int i = tid; i < TENC * INPUT; i += 512) {
        const int t  = i / 3;
        const int c_ = i - 3 * t;
        x_s[t * 4 + c_] = xb[i];
    }
    const float* fb = force + (size_t)b * (PLEN - 1);
    for (int i = tid; i < PLEN - 1; i += 512) f_s[i] = fb[i];
    if (tid < Hh) h_s[0][tid] = 0.0f;

    // ---- per-thread weights: 16 named v2f = 32 floats (half of row) ----
    const v2f* wr = reinterpret_cast<const v2f*>(W_hh + (size_t)row * Hh + half * 32);
    const v2f m0 = wr[0],  m1 = wr[1],  m2 = wr[2],  m3 = wr[3];
    const v2f m4 = wr[4],  m5 = wr[5],  m6 = wr[6],  m7 = wr[7];
    const v2f m8 = wr[8],  m9 = wr[9],  mA = wr[10], mB = wr[11];
    const v2f mC = wr[12], mD = wr[13], mE = wr[14], mF = wr[15];

    // x-part handled by half==0 lanes only (branch-free via zeroed weights)
    const float hm   = (half == 0) ? 1.0f : 0.0f;
    const float wi0  = hm * W_ih[row * INPUT + 0];
    const float wi1  = hm * W_ih[row * INPUT + 1];
    const float wi2  = hm * W_ih[row * INPUT + 2];
    const float bias = hm * (b_ih[row] + b_hh[row]);

    // activation consts: a = am * rcp(1 + 2^(p*kmul)) + acK   (g==2 -> tanh)
    const float kmul = (g == 2) ? (-2.0f * LOG2E) : (-LOG2E);
    const float am   = (g == 2) ? 2.0f : 1.0f;
    const float acK  = (g == 2) ? -1.0f : 0.0f;

    const float wog = (g < 2 && half == 0) ? W_out[g * Hh + u] : 0.0f;
    const float bo0 = b_out[0], bo1 = b_out[1];

    float c  = 0.0f;
    int   rp = 0;

    __syncthreads();

    // ---- one LSTM step: 8 b128 h-loads, 16 pk_fma, 1 barrier ----
    auto lstm_step = [&](float x0, float x1, float x2, bool do_y) {
        const float4* hq = reinterpret_cast<const float4*>(&h_s[rp][half << 5]);
        float s = fmaf(wi0, x0, bias);
        s = fmaf(wi1, x1, s);
        s = fmaf(wi2, x2, s);
        v2f a0 = {s, 0.0f};
        v2f a1 = {0.0f, 0.0f};
        CHUNK(m0, m1, m2, m3, 0)
        CHUNK(m4, m5, m6, m7, 1)
        CHUNK(m8, m9, mA, mB, 2)
        CHUNK(mC, mD, mE, mF, 3)
        const v2f av = a0 + a1;
        float p = av.x + av.y;
        p += SWZ_XOR4(p);                  // combine the two row-halves

        const float e  = exp2_(p * kmul);  // activation
        const float rr = rcp_(1.0f + e);
        const float a  = fmaf(am, rr, acK);

        float gi, gf, gg, go;              // gather 4 gates within the quad
        QUADB(gi, a, 0x00); QUADB(gf, a, 0x55);
        QUADB(gg, a, 0xAA); QUADB(go, a, 0xFF);

        c = fmaf(gf, c, gi * gg);
        const float h = go * tanh_(c);

        if ((lane & 7) == 0) h_s[rp ^ 1][u] = h;   // one writer per unit

        if (do_y) {                        // per-wave y partials over 8 units
            float yp = wog * h;
            yp += __shfl_xor(yp, 8, 64);
            yp += __shfl_xor(yp, 16, 64);
            yp += __shfl_xor(yp, 32, 64);
            if (lane < 2) y_s[rp ^ 1][lane][wv] = yp;   // lane==g here
        }
        rp ^= 1;
        __syncthreads();
    };

    auto read_y = [&]() -> float2 {
        const float4 q0 = *reinterpret_cast<const float4*>(&y_s[rp][0][0]);
        const float4 q1 = *reinterpret_cast<const float4*>(&y_s[rp][0][4]);
        const float4 q2 = *reinterpret_cast<const float4*>(&y_s[rp][1][0]);
        const float4 q3 = *reinterpret_cast<const float4*>(&y_s[rp][1][4]);
        return make_float2(q0.x + q0.y + q0.z + q0.w + q1.x + q1.y + q1.z + q1.w + bo0,
                           q2.x + q2.y + q2.z + q2.w + q3.x + q3.y + q3.z + q3.w + bo1);
    };

    // ---- encoder ----
    for (int t = 0; t < TENC; ++t) {
        const float4 xq = *reinterpret_cast<const float4*>(&x_s[t * 4]);
        lstm_step(xq.x, xq.y, xq.z, t == TENC - 1);
    }

    float* ob = out + (size_t)b * (PLEN * OUTD);

    // ---- autoregressive decoder ----
    for (int d = 0; d < PLEN - 1; ++d) {
        const float2 y = read_y();
        if (tid == 0) *reinterpret_cast<float2*>(ob + d * OUTD) = y;
        lstm_step(y.x, y.y, f_s[d], true);
    }
    {
        const float2 y = read_y();
        if (tid == 0) *reinterpret_cast<float2*>(ob + (PLEN - 1) * OUTD) = y;
    }
}

extern "C" void kernel_launch(void* const* d_in, const int* in_sizes, int n_in,
                              void* d_out, int out_size, void* d_ws, size_t ws_size,
                              hipStream_t stream) {
    const float* x     = (const float*)d_in[0];
    const float* force = (const float*)d_in[1];
    const float* W_ih  = (const float*)d_in[2];
    const float* W_hh  = (const float*)d_in[3];
    const float* b_ih  = (const float*)d_in[4];
    const float* b_hh  = (const float*)d_in[5];
    const float* W_out = (const float*)d_in[6];
    const float* b_out = (const float*)d_in[7];
    float* out = (float*)d_out;

    lstm_forecast_kernel<<<BATCH, 512, 0, stream>>>(
        x, force, W_ih, W_hh, b_ih, b_hh, W_out, b_out, out);
}

// Round 8
// 657.221 us; speedup vs baseline: 1.4854x; 1.4854x over previous
//
#include <hip/hip_runtime.h>

#define Hh 64
#define INPUT 3
#define OUTD 2
#define BATCH 1024
#define BT 4                    // batches per block (== waves per block)
#define TENC 512
#define PLEN 300
#define GSTR 260                // G_s row stride (f32)
#define HSTR 120                // h_T row stride (u16): 64 h + 4 x-ext + zeros

#define LOG2E 1.44269504088896340736f

typedef short  short8 __attribute__((ext_vector_type(8)));
typedef float  f32x4  __attribute__((ext_vector_type(4)));

__device__ __forceinline__ float sigm_(float x) {
    float t = __builtin_amdgcn_exp2f(-x * LOG2E);
    return __builtin_amdgcn_rcpf(1.0f + t);
}
__device__ __forceinline__ float tanh_(float x) {
    float t = __builtin_amdgcn_exp2f(x * (2.0f * LOG2E));
    return fmaf(-2.0f, __builtin_amdgcn_rcpf(1.0f + t), 1.0f);
}
// split fp32 into bf16 hi + bf16 lo (hi = truncate; lo = bf16(residual))
__device__ __forceinline__ void bf16split(float v, unsigned short& hi, unsigned short& lo) {
    unsigned int b = __float_as_uint(v);
    hi = (unsigned short)(b >> 16);
    float r = v - __uint_as_float((unsigned int)hi << 16);
    lo = (unsigned short)(__float_as_uint(r) >> 16);
}

__global__ __launch_bounds__(256, 1)
void lstm_forecast_kernel(const float* __restrict__ x,
                          const float* __restrict__ force,
                          const float* __restrict__ W_ih,
                          const float* __restrict__ W_hh,
                          const float* __restrict__ b_ih,
                          const float* __restrict__ b_hh,
                          const float* __restrict__ W_out,
                          const float* __restrict__ b_out,
                          float* __restrict__ out)
{
    const int tid  = threadIdx.x;
    const int lane = tid & 63;
    const int wv   = tid >> 6;          // wave 0..3 == batch within block
    const int m    = lane & 15;         // MFMA row-in-tile / B column
    const int kg   = (lane >> 4) * 8;   // k-offset within a K=32 slice
    const int b0   = blockIdx.x * BT;

    __shared__ __align__(16) float          x_s[BT][TENC * INPUT]; // 24 KB
    __shared__ __align__(16) float          f_s[BT][PLEN - 1];     // ~4.8 KB
    __shared__ __align__(16) float          G_s[BT][GSTR];         // 4.2 KB
    __shared__ __align__(16) unsigned short h_hiT[BT][HSTR];       // 960 B
    __shared__ __align__(16) unsigned short h_loT[BT][HSTR];       // 960 B

    // ---- stage x (float4 flat copy; block's 4 batches are contiguous) ----
    {
        const float4* xg = reinterpret_cast<const float4*>(x + (size_t)b0 * TENC * INPUT);
        float4* xs = reinterpret_cast<float4*>(&x_s[0][0]);
        for (int i = tid; i < BT * TENC * INPUT / 4; i += 256) xs[i] = xg[i];
        const float* fg = force + (size_t)b0 * (PLEN - 1);
        float* fs = &f_s[0][0];
        for (int i = tid; i < BT * (PLEN - 1); i += 256) fs[i] = fg[i];
        unsigned short* hh = &h_hiT[0][0];
        unsigned short* hl = &h_loT[0][0];
        for (int i = tid; i < BT * HSTR; i += 256) { hh[i] = 0; hl[i] = 0; }
    }
    __syncthreads();
    // constants + x-ext for t=0:  input vec = [h(64); x0,x1,x2,1; 0...]
    if (tid < BT) h_hiT[tid][64 + 3] = 0x3F80;   // 1.0 bf16 (lo stays 0)
    if (tid < BT * 4 && (tid & 3) < 3) {
        const int bb = tid >> 2, j = tid & 3;
        unsigned short xh, xl; bf16split(x_s[bb][j], xh, xl);
        h_hiT[bb][64 + j] = xh; h_loT[bb][64 + j] = xl;
    }

    // ---- A-fragments: rows 64*wv .. 64*wv+63 (gate wv), K=96, hi/lo ----
    short8 Ahi[4][3], Alo[4][3];
    #pragma unroll
    for (int i = 0; i < 4; ++i) {
        const int row = 64 * wv + 16 * i + m;
        #pragma unroll
        for (int ks = 0; ks < 2; ++ks) {
            const float* wp = W_hh + (size_t)row * Hh + ks * 32 + kg;
            short8 h8 = {0,0,0,0,0,0,0,0}, l8 = {0,0,0,0,0,0,0,0};
            #pragma unroll
            for (int j = 0; j < 8; ++j) {
                unsigned short h_, l_; bf16split(wp[j], h_, l_);
                h8[j] = (short)h_; l8[j] = (short)l_;
            }
            Ahi[i][ks] = h8; Alo[i][ks] = l8;
        }
        {   // ks==2: [W_ih row | bias | zeros]
            short8 h8 = {0,0,0,0,0,0,0,0}, l8 = {0,0,0,0,0,0,0,0};
            if (kg == 0) {
                float v0 = W_ih[row * INPUT + 0], v1 = W_ih[row * INPUT + 1];
                float v2 = W_ih[row * INPUT + 2], v3 = b_ih[row] + b_hh[row];
                unsigned short h_, l_;
                bf16split(v0, h_, l_); h8[0] = h_; l8[0] = l_;
                bf16split(v1, h_, l_); h8[1] = h_; l8[1] = l_;
                bf16split(v2, h_, l_); h8[2] = h_; l8[2] = l_;
                bf16split(v3, h_, l_); h8[3] = h_; l8[3] = l_;
            }
            Ahi[i][2] = h8; Alo[i][2] = l8;
        }
    }

    const float wo0 = W_out[lane];
    const float wo1 = W_out[Hh + lane];
    const float bo0 = b_out[0], bo1 = b_out[1];
    float* outb = out + (size_t)(b0 + wv) * (PLEN * OUTD);

    float c = 0.0f;
    __syncthreads();

    // ---- phase 1: G[256 x 16] = A @ [h;x;1]  (hi/lo split, 36 MFMA) ----
    auto phase1 = [&]() {
        const int bcl = lane & 3;       // clamped batch col (cols 4..15 dup)
        short8 bh[3], bl[3];
        #pragma unroll
        for (int ks = 0; ks < 3; ++ks) {
            bh[ks] = *reinterpret_cast<const short8*>(&h_hiT[bcl][ks * 32 + kg]);
            bl[ks] = *reinterpret_cast<const short8*>(&h_loT[bcl][ks * 32 + kg]);
        }
        #pragma unroll
        for (int i = 0; i < 4; ++i) {
            f32x4 acc = {0.0f, 0.0f, 0.0f, 0.0f};
            #pragma unroll
            for (int ks = 0; ks < 3; ++ks) {
                acc = __builtin_amdgcn_mfma_f32_16x16x32_bf16(Ahi[i][ks], bh[ks], acc, 0, 0, 0);
                acc = __builtin_amdgcn_mfma_f32_16x16x32_bf16(Alo[i][ks], bh[ks], acc, 0, 0, 0);
                acc = __builtin_amdgcn_mfma_f32_16x16x32_bf16(Ahi[i][ks], bl[ks], acc, 0, 0, 0);
            }
            if (m < BT) {
                *reinterpret_cast<f32x4*>(&G_s[m][64 * wv + 16 * i + (lane >> 4) * 4]) = acc;
            }
        }
    };

    // ---- phase 2: gate math (wave == batch, lane == unit) ----
    auto phase2 = [&](bool do_y, int dpos, int fidx, bool enc_next, int tnext) {
        const float gi = G_s[wv][lane];
        const float gf = G_s[wv][64 + lane];
        const float gg = G_s[wv][128 + lane];
        const float go = G_s[wv][192 + lane];
        const float si = sigm_(gi);
        const float sf = sigm_(gf);
        const float sg = tanh_(gg);
        const float so = sigm_(go);
        c = fmaf(sf, c, si * sg);
        const float h = so * tanh_(c);
        unsigned short hh, hl; bf16split(h, hh, hl);
        h_hiT[wv][lane] = hh;
        h_loT[wv][lane] = hl;
        if (enc_next && lane < 3) {
            unsigned short xh, xl; bf16split(x_s[wv][tnext * INPUT + lane], xh, xl);
            h_hiT[wv][64 + lane] = xh; h_loT[wv][64 + lane] = xl;
        }
        if (do_y) {
            float p0 = wo0 * h, p1 = wo1 * h;
            #pragma unroll
            for (int msk = 1; msk < 64; msk <<= 1) {
                p0 += __shfl_xor(p0, msk, 64);
                p1 += __shfl_xor(p1, msk, 64);
            }
            const float y0 = p0 + bo0, y1 = p1 + bo1;
            if (lane == 0) *reinterpret_cast<float2*>(outb + dpos * OUTD) = make_float2(y0, y1);
            if (lane < 3) {
                const float v = (lane == 0) ? y0 : (lane == 1) ? y1 : f_s[wv][fidx];
                unsigned short xh, xl; bf16split(v, xh, xl);
                h_hiT[wv][64 + lane] = xh; h_loT[wv][64 + lane] = xl;
            }
        }
    };

    // ---- encoder: 512 steps; last one emits y0 -> out[0] ----
    for (int t = 0; t < TENC; ++t) {
        phase1();
        __syncthreads();
        if (t < TENC - 1) phase2(false, 0, 0, true, t + 1);
        else              phase2(true, 0, 0, false, 0);
        __syncthreads();
    }
    // ---- decoder: 299 steps; step s uses x-ext=[y_s, f[s]] -> out[s+1] ----
    for (int s = 0; s < PLEN - 1; ++s) {
        phase1();
        __syncthreads();
        const int fnext = (s + 1 <= PLEN - 2) ? (s + 1) : (PLEN - 2);
        phase2(true, s + 1, fnext, false, 0);
        __syncthreads();
    }
}

extern "C" void kernel_launch(void* const* d_in, const int* in_sizes, int n_in,
                              void* d_out, int out_size, void* d_ws, size_t ws_size,
                              hipStream_t stream) {
    const float* x     = (const float*)d_in[0];
    const float* force = (const float*)d_in[1];
    const float* W_ih  = (const float*)d_in[2];
    const float* W_hh  = (const float*)d_in[3];
    const float* b_ih  = (const float*)d_in[4];
    const float* b_hh  = (const float*)d_in[5];
    const float* W_out = (const float*)d_in[6];
    const float* b_out = (const float*)d_in[7];
    float* out = (float*)d_out;

    lstm_forecast_kernel<<<BATCH / BT, 256, 0, stream>>>(
        x, force, W_ih, W_hh, b_ih, b_hh, W_out, b_out, out);
}

// Round 9
// 616.631 us; speedup vs baseline: 1.5832x; 1.0658x over previous
//
#include <hip/hip_runtime.h>

#define Hh 64
#define INPUT 3
#define OUTD 2
#define BATCH 1024
#define NBB 4                 // batches per block
#define TENC 512
#define PLEN 300
#define GP 260                // G_s row stride (f32), 16B-aligned, bank-spread
#define HP 80                 // h strip stride (u16) = 160B, 16B-aligned

#define LOG2E 1.44269504088896340736f

typedef short  short8 __attribute__((ext_vector_type(8)));
typedef float  f32x4  __attribute__((ext_vector_type(4)));

__device__ __forceinline__ float sigm_(float x) {
    return __builtin_amdgcn_rcpf(1.0f + __builtin_amdgcn_exp2f(-x * LOG2E));
}
__device__ __forceinline__ float tanh_(float x) {
    return fmaf(-2.0f, __builtin_amdgcn_rcpf(1.0f + __builtin_amdgcn_exp2f(x * (2.0f * LOG2E))), 1.0f);
}
__device__ __forceinline__ void bf16split(float v, unsigned short& hi, unsigned short& lo) {
    unsigned int b = __float_as_uint(v);
    hi = (unsigned short)(b >> 16);
    float r = v - __uint_as_float((unsigned int)hi << 16);
    lo = (unsigned short)(__float_as_uint(r) >> 16);
}

#define MFMA16(A, B, C) __builtin_amdgcn_mfma_f32_16x16x32_bf16((A), (B), (C), 0, 0, 0)

__global__ __launch_bounds__(512, 2)
void lstm_forecast_kernel(const float* __restrict__ x,
                          const float* __restrict__ force,
                          const float* __restrict__ W_ih,
                          const float* __restrict__ W_hh,
                          const float* __restrict__ b_ih,
                          const float* __restrict__ b_hh,
                          const float* __restrict__ W_out,
                          const float* __restrict__ b_out,
                          float* __restrict__ out)
{
    const int tid  = threadIdx.x;
    const int lane = tid & 63;
    const int wv   = tid >> 6;        // wave 0..7; owns row-tiles {2wv, 2wv+1}
    const int m    = lane & 15;       // A row-in-tile / B col (batch)
    const int g4   = lane >> 4;       // k-group
    const int kg   = g4 * 8;
    const int bb   = wv >> 1;         // phase2 batch (wave pair -> batch)
    const int odd  = wv & 1;          // even: h-writer, odd: y-emitter
    const int u    = lane;            // phase2 unit
    const int b0   = blockIdx.x * NBB;

    __shared__ __align__(16) float          x_s[NBB][TENC * 4];  // 32 KB
    __shared__ __align__(16) float          f_s[NBB][PLEN - 1];  // ~4.8 KB
    __shared__ __align__(16) float          G_s[NBB][GP];        // ~4.2 KB
    __shared__ __align__(16) unsigned short h_hi[NBB * HP];      // 640 B
    __shared__ __align__(16) unsigned short h_lo[NBB * HP];      // 640 B

    // ---- stage x / force; zero h strips ----
    for (int i = tid; i < NBB * TENC * INPUT; i += 512) {
        const int b_  = i / (TENC * INPUT);
        const int rem = i - b_ * (TENC * INPUT);
        const int t   = rem / 3;
        const int c_  = rem - 3 * t;
        x_s[b_][t * 4 + c_] = x[(size_t)(b0 + b_) * (TENC * INPUT) + rem];
    }
    for (int i = tid; i < NBB * (PLEN - 1); i += 512) {
        const int b_ = i / (PLEN - 1);
        const int d_ = i - b_ * (PLEN - 1);
        f_s[b_][d_] = force[(size_t)(b0 + b_) * (PLEN - 1) + d_];
    }
    if (tid < NBB * HP) { h_hi[tid] = 0; h_lo[tid] = 0; }

    // ---- per-lane phase2 constants ----
    float wie[4][3], be[4], wd[4], bd[4];
    const float bo0 = b_out[0], bo1 = b_out[1];
    #pragma unroll
    for (int g_ = 0; g_ < 4; ++g_) {
        const int r = g_ * 64 + u;
        wie[g_][0] = W_ih[r * 3 + 0];
        wie[g_][1] = W_ih[r * 3 + 1];
        wie[g_][2] = W_ih[r * 3 + 2];
        be[g_] = b_ih[r] + b_hh[r];
        wd[g_] = wie[g_][2];
        bd[g_] = be[g_] + wie[g_][0] * bo0 + wie[g_][1] * bo1;  // y folded in
    }
    const float wo0 = W_out[u];
    const float wo1 = W_out[64 + u];

    // ---- A fragments: 2 tiles x 2 k-slices, bf16 hi/lo ----
    short8 AH[2][2], AL[2][2];
    auto build_frags = [&](bool aug) {
        #pragma unroll
        for (int TT = 0; TT < 2; ++TT) {
            const int r = (2 * wv + TT) * 16 + m;
            const float wr0 = W_ih[r * 3 + 0];
            const float wr1 = W_ih[r * 3 + 1];
            #pragma unroll
            for (int ks = 0; ks < 2; ++ks) {
                const float* wp = W_hh + (size_t)r * Hh + ks * 32 + kg;
                const float* q0 = W_out + ks * 32 + kg;
                const float* q1 = W_out + 64 + ks * 32 + kg;
                short8 h8, l8;
                #pragma unroll
                for (int j = 0; j < 8; ++j) {
                    float w = wp[j];
                    if (aug) w = fmaf(wr0, q0[j], fmaf(wr1, q1[j], w));  // W' = Whh + Wih01@Wout
                    unsigned short hh_, ll_;
                    bf16split(w, hh_, ll_);
                    h8[j] = (short)hh_; l8[j] = (short)ll_;
                }
                AH[TT][ks] = h8; AL[TT][ks] = l8;
            }
        }
    };
    build_frags(false);

    float c = 0.0f;

    // ---- phase 1: G[256x4] = A'[256x64] @ Hhat[64x4], 12 MFMA/wave ----
    auto phase1 = [&]() {
        const int sb = (m & 3) * HP;
        const short8 bh0 = *reinterpret_cast<const short8*>(&h_hi[sb + kg]);
        const short8 bh1 = *reinterpret_cast<const short8*>(&h_hi[sb + 32 + kg]);
        const short8 bl0 = *reinterpret_cast<const short8*>(&h_lo[sb + kg]);
        const short8 bl1 = *reinterpret_cast<const short8*>(&h_lo[sb + 32 + kg]);
        #pragma unroll
        for (int TT = 0; TT < 2; ++TT) {
            f32x4 acc = {0.0f, 0.0f, 0.0f, 0.0f};
            acc = MFMA16(AH[TT][0], bh0, acc);
            acc = MFMA16(AL[TT][0], bh0, acc);
            acc = MFMA16(AH[TT][0], bl0, acc);
            acc = MFMA16(AH[TT][1], bh1, acc);
            acc = MFMA16(AL[TT][1], bh1, acc);
            acc = MFMA16(AH[TT][1], bl1, acc);
            if (m < 4) {  // cols 0..3 = real batches
                *reinterpret_cast<f32x4*>(&G_s[m][(2 * wv + TT) * 16 + 4 * g4]) = acc;
            }
        }
    };

    auto gates = [&](float pi, float pf, float pg, float po) -> float {
        const float si = sigm_(pi);
        const float sf = sigm_(pf);
        const float sg = tanh_(pg);
        const float so = sigm_(po);
        c = fmaf(sf, c, si * sg);
        return so * tanh_(c);
    };
    auto store_h = [&](float h) {
        unsigned short hh_, hl_;
        bf16split(h, hh_, hl_);
        h_hi[bb * HP + u] = hh_;
        h_lo[bb * HP + u] = hl_;
    };
    auto emit_y = [&](float h, int pos) {
        float p0 = wo0 * h, p1 = wo1 * h;
        #pragma unroll
        for (int msk = 1; msk < 64; msk <<= 1) {
            p0 += __shfl_xor(p0, msk, 64);
            p1 += __shfl_xor(p1, msk, 64);
        }
        if (lane == 0) {
            *reinterpret_cast<float2*>(out + (size_t)(b0 + bb) * (PLEN * OUTD) + pos * OUTD)
                = make_float2(p0 + bo0, p1 + bo1);
        }
    };

    __syncthreads();

    // ---- encoder ----
    for (int t = 0; t < TENC; ++t) {
        phase1();
        __syncthreads();
        const float4 xq = *reinterpret_cast<const float4*>(&x_s[bb][t * 4]);
        float pi = G_s[bb][u]       + be[0];
        float pf = G_s[bb][64 + u]  + be[1];
        float pg = G_s[bb][128 + u] + be[2];
        float po = G_s[bb][192 + u] + be[3];
        pi = fmaf(wie[0][0], xq.x, pi); pi = fmaf(wie[0][1], xq.y, pi); pi = fmaf(wie[0][2], xq.z, pi);
        pf = fmaf(wie[1][0], xq.x, pf); pf = fmaf(wie[1][1], xq.y, pf); pf = fmaf(wie[1][2], xq.z, pf);
        pg = fmaf(wie[2][0], xq.x, pg); pg = fmaf(wie[2][1], xq.y, pg); pg = fmaf(wie[2][2], xq.z, pg);
        po = fmaf(wie[3][0], xq.x, po); po = fmaf(wie[3][1], xq.y, po); po = fmaf(wie[3][2], xq.z, po);
        const float h = gates(pi, pf, pg, po);
        if (!odd)                store_h(h);
        else if (t == TENC - 1)  emit_y(h, 0);   // y0 from h_enc
        __syncthreads();
    }

    // ---- switch to augmented recurrence for the decoder ----
    build_frags(true);

    // ---- autoregressive decoder: y never enters the critical path ----
    for (int s = 0; s < PLEN - 1; ++s) {
        phase1();
        __syncthreads();
        const float fv = f_s[bb][s];
        float pi = G_s[bb][u]       + fmaf(wd[0], fv, bd[0]);
        float pf = G_s[bb][64 + u]  + fmaf(wd[1], fv, bd[1]);
        float pg = G_s[bb][128 + u] + fmaf(wd[2], fv, bd[2]);
        float po = G_s[bb][192 + u] + fmaf(wd[3], fv, bd[3]);
        const float h = gates(pi, pf, pg, po);
        if (!odd) store_h(h);
        else      emit_y(h, s + 1);
        __syncthreads();
    }
}

extern "C" void kernel_launch(void* const* d_in, const int* in_sizes, int n_in,
                              void* d_out, int out_size, void* d_ws, size_t ws_size,
                              hipStream_t stream) {
    const float* x     = (const float*)d_in[0];
    const float* force = (const float*)d_in[1];
    const float* W_ih  = (const float*)d_in[2];
    const float* W_hh  = (const float*)d_in[3];
    const float* b_ih  = (const float*)d_in[4];
    const float* b_hh  = (const float*)d_in[5];
    const float* W_out = (const float*)d_in[6];
    const float* b_out = (const float*)d_in[7];
    float* out = (float*)d_out;

    lstm_forecast_kernel<<<BATCH / NBB, 512, 0, stream>>>(
        x, force, W_ih, W_hh, b_ih, b_hh, W_out, b_out, out);
}